// Round 1
// baseline (351.321 us; speedup 1.0000x reference)
//
#include <hip/hip_runtime.h>
#include <hip/hip_bf16.h>
#include <math.h>

#define TOTAL_B 2
#define SEQ 2048
#define EMB 1024
#define NH 16
#define HD 64
#define M_GEMM (TOTAL_B*SEQ)   // 4096
#define N_GEMM (3*EMB)         // 3072
#define K_GEMM EMB             // 1024

typedef __attribute__((ext_vector_type(8))) short short8;
typedef __attribute__((ext_vector_type(4))) float f32x4;

static __device__ __forceinline__ short f2bf(float f) {
  union { float f; unsigned u; } v; v.f = f;
  unsigned r = v.u + 0x7fff + ((v.u >> 16) & 1u);
  return (short)(r >> 16);
}

static __device__ __forceinline__ void gload_lds16(const void* g, void* l) {
  __builtin_amdgcn_global_load_lds(
      (const __attribute__((address_space(1))) void*)(uintptr_t)g,
      (__attribute__((address_space(3))) void*)(uintptr_t)l, 16, 0, 0);
}

// ---------------- fp32 -> bf16 convert ----------------
__global__ void cvt_kernel(const float* __restrict__ x, const float* __restrict__ w,
                           short* __restrict__ xb, short* __restrict__ wb) {
  const long nx = (long)M_GEMM * K_GEMM;   // 4194304
  const long nw = (long)N_GEMM * K_GEMM;   // 3145728
  long i = (long)blockIdx.x * blockDim.x + threadIdx.x; // unit: 8 elems
  const long tot = (nx + nw) / 8;
  if (i >= tot) return;
  long e = i * 8;
  const float* s; short* d;
  if (e < nx) { s = x + e; d = xb + e; }
  else        { s = w + (e - nx); d = wb + (e - nx); }
  float4 a = ((const float4*)s)[0];
  float4 b = ((const float4*)s)[1];
  short8 o;
  o[0]=f2bf(a.x); o[1]=f2bf(a.y); o[2]=f2bf(a.z); o[3]=f2bf(a.w);
  o[4]=f2bf(b.x); o[5]=f2bf(b.y); o[6]=f2bf(b.z); o[7]=f2bf(b.w);
  *(short8*)d = o;
}

// ---------------- QKV GEMM: C[m,f] = sum_e A[m,e]*W[f,e], outputs split to K/Q/V bf16 [B,H,S,D] ----------------
__global__ __launch_bounds__(256) void qkv_gemm(const short* __restrict__ A, const short* __restrict__ Bm,
                                                short* __restrict__ Kb, short* __restrict__ Qb,
                                                short* __restrict__ Vb) {
  __shared__ __align__(16) short As[128*64];
  __shared__ __align__(16) short Bs[128*64];
  const int tid = threadIdx.x;
  const int lane = tid & 63, wid = tid >> 6;
  const int lr = lane & 15, lg = lane >> 4;
  const int m0 = blockIdx.y * 128, n0 = blockIdx.x * 128;
  const int wm = (wid >> 1) * 64, wn = (wid & 1) * 64;

  f32x4 acc[4][4] = {};

  for (int kt = 0; kt < K_GEMM/64; ++kt) {
#pragma unroll
    for (int i = 0; i < 4; ++i) {
      const int e16 = i*256 + tid;         // 16B chunk id, 0..1023
      const int row = e16 >> 3;            // 0..127
      const int ch  = e16 & 7;
      const int sch = ch ^ (row & 7);      // pre-swizzled global source
      const short* ga = A  + (size_t)(m0 + row)*K_GEMM + kt*64 + sch*8;
      gload_lds16(ga, As + i*2048 + wid*512);
      const short* gb = Bm + (size_t)(n0 + row)*K_GEMM + kt*64 + sch*8;
      gload_lds16(gb, Bs + i*2048 + wid*512);
    }
    __syncthreads();
#pragma unroll
    for (int kk = 0; kk < 2; ++kk) {
      short8 af[4], bfr[4];
#pragma unroll
      for (int mi = 0; mi < 4; ++mi) {
        const int r = wm + mi*16 + lr;
        const int c = (kk*4 + lg) ^ (r & 7);
        af[mi] = *(const short8*)(As + r*64 + c*8);
      }
#pragma unroll
      for (int ni = 0; ni < 4; ++ni) {
        const int r = wn + ni*16 + lr;
        const int c = (kk*4 + lg) ^ (r & 7);
        bfr[ni] = *(const short8*)(Bs + r*64 + c*8);
      }
#pragma unroll
      for (int mi = 0; mi < 4; ++mi)
#pragma unroll
        for (int ni = 0; ni < 4; ++ni)
          acc[mi][ni] = __builtin_amdgcn_mfma_f32_16x16x32_bf16(af[mi], bfr[ni], acc[mi][ni], 0, 0, 0);
    }
    __syncthreads();
  }

  // epilogue: C layout col = lane&15, row = (lane>>4)*4 + reg
#pragma unroll
  for (int mi = 0; mi < 4; ++mi) {
#pragma unroll
    for (int ni = 0; ni < 4; ++ni) {
#pragma unroll
      for (int r = 0; r < 4; ++r) {
        const int m = m0 + wm + mi*16 + lg*4 + r;
        const int f = n0 + wn + ni*16 + lr;
        const int b = m >> 11, s = m & 2047;
        const int which = f >> 10, fl = f & 1023;
        const int h = fl >> 6, d = fl & 63;
        short* dst = (which == 0) ? Kb : (which == 1) ? Qb : Vb;
        dst[((size_t)((b*NH + h)*SEQ + s))*HD + d] = f2bf(acc[mi][ni][r]);
      }
    }
  }
}

// ---------------- V transpose: [bh][s][d] -> [bh][d][s] ----------------
__global__ void vtrans(const short* __restrict__ Vb, short* __restrict__ Vt) {
  __shared__ short t[64][72];
  const int hb = blockIdx.y;
  const int s0 = blockIdx.x * 64;
  const short* src = Vb + ((size_t)hb*SEQ + s0)*HD;
  short* dst = Vt + (size_t)hb*HD*SEQ;
  const int tid = threadIdx.x;
#pragma unroll
  for (int i = 0; i < 2; ++i) {
    const int e = i*2048 + tid*8;
    const int r = e >> 6, c = e & 63;
    short8 v = *(const short8*)(src + (size_t)r*HD + c);
#pragma unroll
    for (int j = 0; j < 8; ++j) t[r][c+j] = v[j];
  }
  __syncthreads();
#pragma unroll
  for (int i = 0; i < 2; ++i) {
    const int e = i*2048 + tid*8;
    const int d = e >> 6, ss = e & 63;
    short8 v;
#pragma unroll
    for (int j = 0; j < 8; ++j) v[j] = t[ss+j][d];
    *(short8*)(dst + (size_t)d*SEQ + s0 + ss) = v;
  }
}

// ---------------- flash attention with ALiBi + causal ----------------
__global__ __launch_bounds__(256) void attn_kernel(const short* __restrict__ Kb, const short* __restrict__ Qb,
                                                   const short* __restrict__ Vt, float* __restrict__ Out) {
  __shared__ __align__(16) short Plds[4][1024];
  const int tid = threadIdx.x, lane = tid & 63, wid = tid >> 6;
  const int lr = lane & 15, lg = lane >> 4;
  const int qt = blockIdx.x, bh = blockIdx.y;
  const int b = bh >> 4, h = bh & 15;
  const int q0 = qt * 64, qrb = q0 + wid * 16;
  const float slope = exp2f(-0.5f * (float)(h + 1));
  const short* Kp = Kb + (size_t)bh * SEQ * HD;
  const short* Qp = Qb + (size_t)bh * SEQ * HD;
  const short* Vp = Vt + (size_t)bh * HD * SEQ;

  short8 qf[2];
#pragma unroll
  for (int kk = 0; kk < 2; ++kk)
    qf[kk] = *(const short8*)(Qp + (size_t)(qrb + lr)*HD + kk*32 + lg*8);

  float m_run[4], l_run[4];
  f32x4 o[4] = {};
#pragma unroll
  for (int r = 0; r < 4; ++r) { m_run[r] = -INFINITY; l_run[r] = 0.f; }

  short* myP = &Plds[wid][0];
  const int nt = qt + 1;
  for (int t = 0; t < nt; ++t) {
    const int kv0 = t * 64;
    // QK^T: S[q][kv], 16x64 per wave
    f32x4 sc[4];
#pragma unroll
    for (int kvf = 0; kvf < 4; ++kvf) {
      f32x4 s = {};
#pragma unroll
      for (int kk = 0; kk < 2; ++kk) {
        short8 kf = *(const short8*)(Kp + (size_t)(kv0 + kvf*16 + lr)*HD + kk*32 + lg*8);
        s = __builtin_amdgcn_mfma_f32_16x16x32_bf16(qf[kk], kf, s, 0, 0, 0);
      }
      sc[kvf] = s;
    }
    // bias + causal mask (C layout: row q = lg*4+r, col kv = lr)
    float pv[4][4];
    float mt[4];
#pragma unroll
    for (int r = 0; r < 4; ++r) mt[r] = -INFINITY;
#pragma unroll
    for (int kvf = 0; kvf < 4; ++kvf) {
      const int j = kv0 + kvf*16 + lr;
#pragma unroll
      for (int r = 0; r < 4; ++r) {
        const int iq = qrb + lg*4 + r;
        const float v = (j <= iq) ? (sc[kvf][r] * 0.03125f + slope * (float)(j - iq)) : -INFINITY;
        pv[kvf][r] = v;
        mt[r] = fmaxf(mt[r], v);
      }
    }
#pragma unroll
    for (int off = 1; off < 16; off <<= 1)
#pragma unroll
      for (int r = 0; r < 4; ++r)
        mt[r] = fmaxf(mt[r], __shfl_xor(mt[r], off, 64));
    float corr[4], lt[4];
#pragma unroll
    for (int r = 0; r < 4; ++r) {
      const float mn = fmaxf(m_run[r], mt[r]);
      corr[r] = __expf(m_run[r] - mn);
      m_run[r] = mn;
      lt[r] = 0.f;
    }
#pragma unroll
    for (int kvf = 0; kvf < 4; ++kvf)
#pragma unroll
      for (int r = 0; r < 4; ++r) {
        const float p = __expf(pv[kvf][r] - m_run[r]);
        pv[kvf][r] = p;
        lt[r] += p;
      }
#pragma unroll
    for (int off = 1; off < 16; off <<= 1)
#pragma unroll
      for (int r = 0; r < 4; ++r)
        lt[r] += __shfl_xor(lt[r], off, 64);
#pragma unroll
    for (int r = 0; r < 4; ++r)
      l_run[r] = l_run[r]*corr[r] + lt[r];
#pragma unroll
    for (int dt = 0; dt < 4; ++dt)
#pragma unroll
      for (int r = 0; r < 4; ++r)
        o[dt][r] *= corr[r];
    // P -> per-wave LDS (bf16, XOR-swizzled chunks)
#pragma unroll
    for (int kvf = 0; kvf < 4; ++kvf)
#pragma unroll
      for (int r = 0; r < 4; ++r) {
        const int qloc = lg*4 + r;
        const int kvl = kvf*16 + lr;
        const int sch = (kvl >> 3) ^ (qloc & 7);
        myP[qloc*64 + sch*8 + (kvl & 7)] = f2bf(pv[kvf][r]);
      }
    // PV: O[q][d] += P[q][kv] * V[kv][d]
#pragma unroll
    for (int ks = 0; ks < 2; ++ks) {
      const int c = (ks*4 + lg) ^ (lr & 7);
      const short8 pf = *(const short8*)(myP + lr*64 + c*8);
#pragma unroll
      for (int dt = 0; dt < 4; ++dt) {
        const short8 vf = *(const short8*)(Vp + (size_t)(dt*16 + lr)*SEQ + kv0 + ks*32 + lg*8);
        o[dt] = __builtin_amdgcn_mfma_f32_16x16x32_bf16(pf, vf, o[dt], 0, 0, 0);
      }
    }
  }
  // output: fp32 [B,S,E]
  float* Ob = Out + (size_t)b*SEQ*EMB + (size_t)h*HD;
#pragma unroll
  for (int dt = 0; dt < 4; ++dt)
#pragma unroll
    for (int r = 0; r < 4; ++r) {
      const int iq = qrb + lg*4 + r;
      Ob[(size_t)iq*EMB + dt*16 + lr] = o[dt][r] / l_run[r];
    }
}

extern "C" void kernel_launch(void* const* d_in, const int* in_sizes, int n_in,
                              void* d_out, int out_size, void* d_ws, size_t ws_size,
                              hipStream_t stream) {
  const float* x = (const float*)d_in[0];
  const float* w = (const float*)d_in[1];
  char* ws = (char*)d_ws;
  // layout (bytes): xb 8MB | wb 6MB | Kb 8MB | Qb 8MB | Vb 8MB ; Vt reuses xb region
  if (ws_size < 39845888u) return;
  short* xb = (short*)(ws);
  short* wb = (short*)(ws + 8388608u);
  short* Kb = (short*)(ws + 14680064u);
  short* Qb = (short*)(ws + 23068672u);
  short* Vb = (short*)(ws + 31457280u);
  short* Vt = xb;  // GEMM has consumed xb before vtrans runs
  float* out = (float*)d_out;

  cvt_kernel<<<3584, 256, 0, stream>>>(x, w, xb, wb);
  qkv_gemm<<<dim3(N_GEMM/128, M_GEMM/128), 256, 0, stream>>>(xb, wb, Kb, Qb, Vb);
  vtrans<<<dim3(SEQ/64, TOTAL_B*NH), 256, 0, stream>>>(Vb, Vt);
  attn_kernel<<<dim3(SEQ/64, TOTAL_B*NH), 256, 0, stream>>>(Kb, Qb, Vt, out);
}

// Round 2
// 132.574 us; speedup vs baseline: 2.6500x; 2.6500x over previous
//
#include <hip/hip_runtime.h>
#include <hip/hip_bf16.h>
#include <math.h>

#define TOTAL_B 2
#define SEQ 2048
#define EMB 1024
#define NH 16
#define HD 64
#define M_GEMM (TOTAL_B*SEQ)   // 4096
#define N_GEMM (3*EMB)         // 3072
#define K_GEMM EMB             // 1024

typedef __attribute__((ext_vector_type(8))) short short8;
typedef __attribute__((ext_vector_type(4))) float f32x4;

static __device__ __forceinline__ short f2bf(float f) {
  union { float f; unsigned u; } v; v.f = f;
  unsigned r = v.u + 0x7fff + ((v.u >> 16) & 1u);
  return (short)(r >> 16);
}

static __device__ __forceinline__ void gload_lds16(const void* g, void* l) {
  __builtin_amdgcn_global_load_lds(
      (const __attribute__((address_space(1))) void*)(uintptr_t)g,
      (__attribute__((address_space(3))) void*)(uintptr_t)l, 16, 0, 0);
}

// ---------------- fp32 -> bf16 convert ----------------
__global__ void cvt_kernel(const float* __restrict__ x, const float* __restrict__ w,
                           short* __restrict__ xb, short* __restrict__ wb) {
  const long nx = (long)M_GEMM * K_GEMM;
  const long nw = (long)N_GEMM * K_GEMM;
  long i = (long)blockIdx.x * blockDim.x + threadIdx.x;
  const long tot = (nx + nw) / 8;
  if (i >= tot) return;
  long e = i * 8;
  const float* s; short* d;
  if (e < nx) { s = x + e; d = xb + e; }
  else        { s = w + (e - nx); d = wb + (e - nx); }
  float4 a = ((const float4*)s)[0];
  float4 b = ((const float4*)s)[1];
  short8 o;
  o[0]=f2bf(a.x); o[1]=f2bf(a.y); o[2]=f2bf(a.z); o[3]=f2bf(a.w);
  o[4]=f2bf(b.x); o[5]=f2bf(b.y); o[6]=f2bf(b.z); o[7]=f2bf(b.w);
  *(short8*)d = o;
}

// ---------------- QKV GEMM ----------------
__global__ __launch_bounds__(256) void qkv_gemm(const short* __restrict__ A, const short* __restrict__ Bm,
                                                short* __restrict__ Kb, short* __restrict__ Qb,
                                                short* __restrict__ Vb) {
  __shared__ __align__(16) short As[128*64];
  __shared__ __align__(16) short Bs[128*64];
  const int tid = threadIdx.x;
  const int lane = tid & 63, wid = tid >> 6;
  const int lr = lane & 15, lg = lane >> 4;
  const int m0 = blockIdx.y * 128, n0 = blockIdx.x * 128;
  const int wm = (wid >> 1) * 64, wn = (wid & 1) * 64;

  f32x4 acc[4][4] = {};

  for (int kt = 0; kt < K_GEMM/64; ++kt) {
#pragma unroll
    for (int i = 0; i < 4; ++i) {
      const int e16 = i*256 + tid;
      const int row = e16 >> 3;
      const int ch  = e16 & 7;
      const int sch = ch ^ (row & 7);
      const short* ga = A  + (size_t)(m0 + row)*K_GEMM + kt*64 + sch*8;
      gload_lds16(ga, As + i*2048 + wid*512);
      const short* gb = Bm + (size_t)(n0 + row)*K_GEMM + kt*64 + sch*8;
      gload_lds16(gb, Bs + i*2048 + wid*512);
    }
    __syncthreads();
#pragma unroll
    for (int kk = 0; kk < 2; ++kk) {
      short8 af[4], bfr[4];
#pragma unroll
      for (int mi = 0; mi < 4; ++mi) {
        const int r = wm + mi*16 + lr;
        const int c = (kk*4 + lg) ^ (r & 7);
        af[mi] = *(const short8*)(As + r*64 + c*8);
      }
#pragma unroll
      for (int ni = 0; ni < 4; ++ni) {
        const int r = wn + ni*16 + lr;
        const int c = (kk*4 + lg) ^ (r & 7);
        bfr[ni] = *(const short8*)(Bs + r*64 + c*8);
      }
#pragma unroll
      for (int mi = 0; mi < 4; ++mi)
#pragma unroll
        for (int ni = 0; ni < 4; ++ni)
          acc[mi][ni] = __builtin_amdgcn_mfma_f32_16x16x32_bf16(af[mi], bfr[ni], acc[mi][ni], 0, 0, 0);
    }
    __syncthreads();
  }

#pragma unroll
  for (int mi = 0; mi < 4; ++mi) {
#pragma unroll
    for (int ni = 0; ni < 4; ++ni) {
#pragma unroll
      for (int r = 0; r < 4; ++r) {
        const int m = m0 + wm + mi*16 + lg*4 + r;
        const int f = n0 + wn + ni*16 + lr;
        const int b = m >> 11, s = m & 2047;
        const int which = f >> 10, fl = f & 1023;
        const int h = fl >> 6, d = fl & 63;
        short* dst = (which == 0) ? Kb : (which == 1) ? Qb : Vb;
        float val = acc[mi][ni][r];
        if (which == 1) val *= 0.03125f;   // fold 1/sqrt(E)=1/32 into Q (exact in bf16)
        dst[((size_t)((b*NH + h)*SEQ + s))*HD + d] = f2bf(val);
      }
    }
  }
}

// ---------------- V transpose: [bh][s][d] -> [bh][d][s] ----------------
__global__ void vtrans(const short* __restrict__ Vb, short* __restrict__ Vt) {
  __shared__ short t[64][72];
  const int hb = blockIdx.y;
  const int s0 = blockIdx.x * 64;
  const short* src = Vb + ((size_t)hb*SEQ + s0)*HD;
  short* dst = Vt + (size_t)hb*HD*SEQ;
  const int tid = threadIdx.x;
#pragma unroll
  for (int i = 0; i < 2; ++i) {
    const int e = i*2048 + tid*8;
    const int r = e >> 6, c = e & 63;
    short8 v = *(const short8*)(src + (size_t)r*HD + c);
#pragma unroll
    for (int j = 0; j < 8; ++j) t[r][c+j] = v[j];
  }
  __syncthreads();
#pragma unroll
  for (int i = 0; i < 2; ++i) {
    const int e = i*2048 + tid*8;
    const int d = e >> 6, ss = e & 63;
    short8 v;
#pragma unroll
    for (int j = 0; j < 8; ++j) v[j] = t[ss+j][d];
    *(short8*)(dst + (size_t)d*SEQ + s0 + ss) = v;
  }
}

// ---------------- flash attention v2: LDS-staged K/V dbuf + paired q-tiles ----------------
__global__ __launch_bounds__(256) void attn_kernel(const short* __restrict__ Kb, const short* __restrict__ Qb,
                                                   const short* __restrict__ Vt, float* __restrict__ Out) {
  __shared__ __align__(16) short Ks[2][64*64];
  __shared__ __align__(16) short Vs[2][64*64];
  __shared__ __align__(16) short Plds[4][16*64];
  const int tid = threadIdx.x, lane = tid & 63, wid = tid >> 6;
  const int lr = lane & 15, lg = lane >> 4;
  const int bh = blockIdx.y;
  const int b = bh >> 4, h = bh & 15;
  const float slope = exp2f(-0.5f * (float)(h + 1));
  const short* Kp = Kb + (size_t)bh * SEQ * HD;
  const short* Qp = Qb + (size_t)bh * SEQ * HD;
  const short* Vp = Vt + (size_t)bh * HD * SEQ;
  float* Ob = Out + (size_t)b*SEQ*EMB + (size_t)h*HD;
  short* myP = &Plds[wid][0];

  // stage K tile + V tile (16KB) into LDS buf; linear dest, XOR-swizzled global source
  auto stage = [&](int buf, int t) {
    const int kv0 = t * 64;
#pragma unroll
    for (int i = 0; i < 2; ++i) {
      const int e16 = i*256 + tid;
      const int row = e16 >> 3, ch = e16 & 7;
      const int sch = ch ^ (row & 7);
      gload_lds16(Kp + (size_t)(kv0 + row)*HD + sch*8, &Ks[buf][i*2048 + wid*512]);
      gload_lds16(Vp + (size_t)row*SEQ + kv0 + sch*8,  &Vs[buf][i*2048 + wid*512]);
    }
  };

  // paired q-tiles: (x, 31-x) -> uniform 33 KV steps per block
#pragma unroll 1
  for (int half = 0; half < 2; ++half) {
    const int qt = half ? (31 - blockIdx.x) : blockIdx.x;
    const int q0 = qt * 64, qrb = q0 + wid * 16;
    const int nt = qt + 1;

    short8 qf[2];
#pragma unroll
    for (int kk = 0; kk < 2; ++kk)
      qf[kk] = *(const short8*)(Qp + (size_t)(qrb + lr)*HD + kk*32 + lg*8);

    float m_run[4], l_run[4];
    f32x4 o[4] = {};
#pragma unroll
    for (int r = 0; r < 4; ++r) { m_run[r] = -INFINITY; l_run[r] = 0.f; }

    int cur = 0;
    stage(0, 0);
    __syncthreads();

#pragma unroll 1
    for (int t = 0; t < nt; ++t) {
      const int kv0 = t * 64;
      if (t + 1 < nt) stage(cur ^ 1, t + 1);   // prefetch next tile (in flight during compute)

      if (kv0 <= qrb + 15) {  // wave-uniform: skip fully-masked tiles
        // QK^T from LDS
        short8 kf[4][2];
#pragma unroll
        for (int kvf = 0; kvf < 4; ++kvf)
#pragma unroll
          for (int kk = 0; kk < 2; ++kk) {
            const int r = kvf*16 + lr, c = (kk*4 + lg) ^ (r & 7);
            kf[kvf][kk] = *(const short8*)(&Ks[cur][r*64 + c*8]);
          }
        f32x4 sc[4];
#pragma unroll
        for (int kvf = 0; kvf < 4; ++kvf) {
          f32x4 s = {};
#pragma unroll
          for (int kk = 0; kk < 2; ++kk)
            s = __builtin_amdgcn_mfma_f32_16x16x32_bf16(qf[kk], kf[kvf][kk], s, 0, 0, 0);
          sc[kvf] = s;
        }
        // bias + (conditional) causal mask; C layout: row q = lg*4+r, col kv = lr
        const bool needMask = (kv0 + 63 > qrb);
        float pv[4][4];
        float mt[4];
#pragma unroll
        for (int r = 0; r < 4; ++r) mt[r] = -INFINITY;
#pragma unroll
        for (int kvf = 0; kvf < 4; ++kvf) {
          const int j = kv0 + kvf*16 + lr;
#pragma unroll
          for (int r = 0; r < 4; ++r) {
            const int iq = qrb + lg*4 + r;
            float v = sc[kvf][r] + slope * (float)(j - iq);
            if (needMask && j > iq) v = -INFINITY;
            pv[kvf][r] = v;
            mt[r] = fmaxf(mt[r], v);
          }
        }
#pragma unroll
        for (int off = 1; off < 16; off <<= 1)
#pragma unroll
          for (int r = 0; r < 4; ++r)
            mt[r] = fmaxf(mt[r], __shfl_xor(mt[r], off, 64));
        float corr[4], lt[4];
#pragma unroll
        for (int r = 0; r < 4; ++r) {
          const float mn = fmaxf(m_run[r], mt[r]);
          corr[r] = __expf(m_run[r] - mn);
          m_run[r] = mn;
          lt[r] = 0.f;
        }
#pragma unroll
        for (int kvf = 0; kvf < 4; ++kvf)
#pragma unroll
          for (int r = 0; r < 4; ++r) {
            const float p = __expf(pv[kvf][r] - m_run[r]);
            pv[kvf][r] = p;
            lt[r] += p;
          }
#pragma unroll
        for (int off = 1; off < 16; off <<= 1)
#pragma unroll
          for (int r = 0; r < 4; ++r)
            lt[r] += __shfl_xor(lt[r], off, 64);
#pragma unroll
        for (int r = 0; r < 4; ++r)
          l_run[r] = l_run[r]*corr[r] + lt[r];
#pragma unroll
        for (int dt = 0; dt < 4; ++dt)
#pragma unroll
          for (int r = 0; r < 4; ++r)
            o[dt][r] *= corr[r];
        // P -> per-wave LDS (bf16, XOR-swizzled)
#pragma unroll
        for (int kvf = 0; kvf < 4; ++kvf)
#pragma unroll
          for (int r = 0; r < 4; ++r) {
            const int qloc = lg*4 + r;
            const int kvl = kvf*16 + lr;
            const int sch = (kvl >> 3) ^ (qloc & 7);
            myP[qloc*64 + sch*8 + (kvl & 7)] = f2bf(pv[kvf][r]);
          }
        // PV from LDS
#pragma unroll
        for (int ks = 0; ks < 2; ++ks) {
          const int cp = (ks*4 + lg) ^ (lr & 7);
          const short8 pf = *(const short8*)(myP + lr*64 + cp*8);
#pragma unroll
          for (int dt = 0; dt < 4; ++dt) {
            const int rv = dt*16 + lr;
            const int cv = (ks*4 + lg) ^ (rv & 7);
            const short8 vf = *(const short8*)(&Vs[cur][rv*64 + cv*8]);
            o[dt] = __builtin_amdgcn_mfma_f32_16x16x32_bf16(pf, vf, o[dt], 0, 0, 0);
          }
        }
      }
      __syncthreads();
      cur ^= 1;
    }

    // output: fp32 [B,S,E]
#pragma unroll
    for (int dt = 0; dt < 4; ++dt)
#pragma unroll
      for (int r = 0; r < 4; ++r) {
        const int iq = qrb + lg*4 + r;
        Ob[(size_t)iq*EMB + dt*16 + lr] = o[dt][r] / l_run[r];
      }
  }
}

extern "C" void kernel_launch(void* const* d_in, const int* in_sizes, int n_in,
                              void* d_out, int out_size, void* d_ws, size_t ws_size,
                              hipStream_t stream) {
  const float* x = (const float*)d_in[0];
  const float* w = (const float*)d_in[1];
  char* ws = (char*)d_ws;
  if (ws_size < 39845888u) return;
  short* xb = (short*)(ws);
  short* wb = (short*)(ws + 8388608u);
  short* Kb = (short*)(ws + 14680064u);
  short* Qb = (short*)(ws + 23068672u);
  short* Vb = (short*)(ws + 31457280u);
  short* Vt = xb;  // GEMM has consumed xb before vtrans runs
  float* out = (float*)d_out;

  cvt_kernel<<<3584, 256, 0, stream>>>(x, w, xb, wb);
  qkv_gemm<<<dim3(N_GEMM/128, M_GEMM/128), 256, 0, stream>>>(xb, wb, Kb, Qb, Vb);
  vtrans<<<dim3(SEQ/64, TOTAL_B*NH), 256, 0, stream>>>(Vb, Vt);
  attn_kernel<<<dim3(16, TOTAL_B*NH), 256, 0, stream>>>(Kb, Qb, Vt, out);
}

// Round 3
// 107.464 us; speedup vs baseline: 3.2692x; 1.2336x over previous
//
#include <hip/hip_runtime.h>
#include <hip/hip_bf16.h>
#include <math.h>

#define TOTAL_B 2
#define SEQ 2048
#define EMB 1024
#define NH 16
#define HD 64
#define M_GEMM (TOTAL_B*SEQ)   // 4096
#define N_GEMM (3*EMB)         // 3072
#define K_GEMM EMB             // 1024

typedef __attribute__((ext_vector_type(8))) short short8;
typedef __attribute__((ext_vector_type(4))) float f32x4;
typedef __attribute__((ext_vector_type(4))) unsigned u32x4;

static __device__ __forceinline__ short f2bf(float f) {
  union { float f; unsigned u; } v; v.f = f;
  unsigned r = v.u + 0x7fff + ((v.u >> 16) & 1u);
  return (short)(r >> 16);
}

static __device__ __forceinline__ void gload_lds16(const void* g, void* l) {
  __builtin_amdgcn_global_load_lds(
      (const __attribute__((address_space(1))) void*)(uintptr_t)g,
      (__attribute__((address_space(3))) void*)(uintptr_t)l, 16, 0, 0);
}

static __device__ __forceinline__ float exp2v(float x) {
  float r; asm("v_exp_f32 %0, %1" : "=v"(r) : "v"(x)); return r;
}
static __device__ __forceinline__ unsigned cvtpk(float lo, float hi) {
  unsigned r; asm("v_cvt_pk_bf16_f32 %0, %1, %2" : "=v"(r) : "v"(lo), "v"(hi)); return r;
}
static __device__ __forceinline__ void pl32swap(unsigned &a, unsigned &b) {
  asm("v_permlane32_swap_b32 %0, %1" : "+v"(a), "+v"(b));
}

// ---------------- fp32 -> bf16 convert ----------------
__global__ void cvt_kernel(const float* __restrict__ x, const float* __restrict__ w,
                           short* __restrict__ xb, short* __restrict__ wb) {
  const long nx = (long)M_GEMM * K_GEMM;
  const long nw = (long)N_GEMM * K_GEMM;
  long i = (long)blockIdx.x * blockDim.x + threadIdx.x;
  const long tot = (nx + nw) / 8;
  if (i >= tot) return;
  long e = i * 8;
  const float* s; short* d;
  if (e < nx) { s = x + e; d = xb + e; }
  else        { s = w + (e - nx); d = wb + (e - nx); }
  float4 a = ((const float4*)s)[0];
  float4 b = ((const float4*)s)[1];
  short8 o;
  o[0]=f2bf(a.x); o[1]=f2bf(a.y); o[2]=f2bf(a.z); o[3]=f2bf(a.w);
  o[4]=f2bf(b.x); o[5]=f2bf(b.y); o[6]=f2bf(b.z); o[7]=f2bf(b.w);
  *(short8*)d = o;
}

// ---------------- QKV GEMM ----------------
__global__ __launch_bounds__(256) void qkv_gemm(const short* __restrict__ A, const short* __restrict__ Bm,
                                                short* __restrict__ Kb, short* __restrict__ Qb,
                                                short* __restrict__ Vb) {
  __shared__ __align__(16) short As[128*64];
  __shared__ __align__(16) short Bs[128*64];
  const int tid = threadIdx.x;
  const int lane = tid & 63, wid = tid >> 6;
  const int lr = lane & 15, lg = lane >> 4;
  const int m0 = blockIdx.y * 128, n0 = blockIdx.x * 128;
  const int wm = (wid >> 1) * 64, wn = (wid & 1) * 64;

  f32x4 acc[4][4] = {};

  for (int kt = 0; kt < K_GEMM/64; ++kt) {
#pragma unroll
    for (int i = 0; i < 4; ++i) {
      const int e16 = i*256 + tid;
      const int row = e16 >> 3;
      const int ch  = e16 & 7;
      const int sch = ch ^ (row & 7);
      const short* ga = A  + (size_t)(m0 + row)*K_GEMM + kt*64 + sch*8;
      gload_lds16(ga, As + i*2048 + wid*512);
      const short* gb = Bm + (size_t)(n0 + row)*K_GEMM + kt*64 + sch*8;
      gload_lds16(gb, Bs + i*2048 + wid*512);
    }
    __syncthreads();
#pragma unroll
    for (int kk = 0; kk < 2; ++kk) {
      short8 af[4], bfr[4];
#pragma unroll
      for (int mi = 0; mi < 4; ++mi) {
        const int r = wm + mi*16 + lr;
        const int c = (kk*4 + lg) ^ (r & 7);
        af[mi] = *(const short8*)(As + r*64 + c*8);
      }
#pragma unroll
      for (int ni = 0; ni < 4; ++ni) {
        const int r = wn + ni*16 + lr;
        const int c = (kk*4 + lg) ^ (r & 7);
        bfr[ni] = *(const short8*)(Bs + r*64 + c*8);
      }
#pragma unroll
      for (int mi = 0; mi < 4; ++mi)
#pragma unroll
        for (int ni = 0; ni < 4; ++ni)
          acc[mi][ni] = __builtin_amdgcn_mfma_f32_16x16x32_bf16(af[mi], bfr[ni], acc[mi][ni], 0, 0, 0);
    }
    __syncthreads();
  }

#pragma unroll
  for (int mi = 0; mi < 4; ++mi) {
#pragma unroll
    for (int ni = 0; ni < 4; ++ni) {
#pragma unroll
      for (int r = 0; r < 4; ++r) {
        const int m = m0 + wm + mi*16 + lg*4 + r;
        const int f = n0 + wn + ni*16 + lr;
        const int b = m >> 11, s = m & 2047;
        const int which = f >> 10, fl = f & 1023;
        const int h = fl >> 6, d = fl & 63;
        short* dst = (which == 0) ? Kb : (which == 1) ? Qb : Vb;
        float val = acc[mi][ni][r];
        if (which == 1) val *= 0.04508422f;   // (1/sqrt(E)) * log2(e) folded into Q
        dst[((size_t)((b*NH + h)*SEQ + s))*HD + d] = f2bf(val);
      }
    }
  }
}

// ---------------- V transpose: [bh][s][d] -> [bh][d][s] ----------------
__global__ void vtrans(const short* __restrict__ Vb, short* __restrict__ Vt) {
  __shared__ short t[64][72];
  const int hb = blockIdx.y;
  const int s0 = blockIdx.x * 64;
  const short* src = Vb + ((size_t)hb*SEQ + s0)*HD;
  short* dst = Vt + (size_t)hb*HD*SEQ;
  const int tid = threadIdx.x;
#pragma unroll
  for (int i = 0; i < 2; ++i) {
    const int e = i*2048 + tid*8;
    const int r = e >> 6, c = e & 63;
    short8 v = *(const short8*)(src + (size_t)r*HD + c);
#pragma unroll
    for (int j = 0; j < 8; ++j) t[r][c+j] = v[j];
  }
  __syncthreads();
#pragma unroll
  for (int i = 0; i < 2; ++i) {
    const int e = i*2048 + tid*8;
    const int d = e >> 6, ss = e & 63;
    short8 v;
#pragma unroll
    for (int j = 0; j < 8; ++j) v[j] = t[ss+j][d];
    *(short8*)(dst + (size_t)d*SEQ + s0 + ss) = v;
  }
}

// ---------------- flash attention v3: swapped QK^T, in-register softmax+P relayout ----------------
__global__ __launch_bounds__(256, 4) void attn_kernel(const short* __restrict__ Kb, const short* __restrict__ Qb,
                                                      const short* __restrict__ Vt, float* __restrict__ Out) {
  __shared__ __align__(16) short Ks[2][64*64];
  __shared__ __align__(16) short Vs[2][64*64];
  const int tid = threadIdx.x, lane = tid & 63, wid = tid >> 6;
  const int lr = lane & 15, lg = lane >> 4;
  const int bh = blockIdx.x;                  // bh on x: same bh -> same XCD (b%8)
  const int b = bh >> 4, h = bh & 15;
  const int qidx = blockIdx.y;
  const int g = qidx >> 3, rq = qidx & 7;     // stratified qt: per-CU work sum constant
  const int qt = (g == 0) ? rq : (g == 1) ? (15 - rq) : (g == 2) ? (16 + rq) : (31 - rq);
  const float slope = exp2f(-0.5f * (float)(h + 1)) * 1.44269504f;  // log2-domain
  const short* Kp = Kb + (size_t)bh * SEQ * HD;
  const short* Qp = Qb + (size_t)bh * SEQ * HD;
  const short* Vp = Vt + (size_t)bh * HD * SEQ;
  float* Ob = Out + (size_t)b * SEQ * EMB + (size_t)h * HD;

  const int q0 = qt * 64, qrb = q0 + wid * 16;
  const int nt = qt + 1;

  // B-frag: Q rows at lane lr (q = qrb + lr)
  short8 qf[2];
#pragma unroll
  for (int kk = 0; kk < 2; ++kk)
    qf[kk] = *(const short8*)(Qp + (size_t)(qrb + lr)*HD + kk*32 + lg*8);

  // A-frag K-row bit-permutation: D-row i holds kv = pi'(kvf,i); pi' bits: b3<-i2 b2<-i1 b1<-i3 b0<-i0
  const int bp = ((lr & 4) << 1) | ((lr & 2) << 1) | ((lr & 8) >> 2) | (lr & 1);
  // per-lane kv offset base: this lane's reg (kvf,r) holds kv = kvf*16 + cl + {0,1,4,5}[r]
  const int cbase = qrb + lr - ((lg & 1) * 8 + (lg >> 1) * 2);

  float m_run = -INFINITY, l_run = 0.f;
  f32x4 o[4] = {};

  auto stage = [&](int buf, int t) {
    const int kv0 = t * 64;
#pragma unroll
    for (int i = 0; i < 2; ++i) {
      const int e16 = i*256 + tid;
      const int row = e16 >> 3, ch = e16 & 7;
      const int sch = ch ^ (row & 7);
      gload_lds16(Kp + (size_t)(kv0 + row)*HD + sch*8, &Ks[buf][i*2048 + wid*512]);
      gload_lds16(Vp + (size_t)row*SEQ + kv0 + sch*8,  &Vs[buf][i*2048 + wid*512]);
    }
  };

  int cur = 0;
  stage(0, 0);
  __syncthreads();

#pragma unroll 1
  for (int t = 0; t < nt; ++t) {
    const int kv0 = t * 64;
    if (t + 1 < nt) stage(cur ^ 1, t + 1);

    if (kv0 <= qrb + 15) {
      // K A-frags (permuted rows)
      short8 kf[4][2];
#pragma unroll
      for (int kvf = 0; kvf < 4; ++kvf) {
        const int row = kvf*16 + bp;
#pragma unroll
        for (int kk = 0; kk < 2; ++kk) {
          const int c = (kk*4 + lg) ^ (row & 7);
          kf[kvf][kk] = *(const short8*)(&Ks[cur][row*64 + c*8]);
        }
      }
      f32x4 sc[4];
      __builtin_amdgcn_s_setprio(1);
#pragma unroll
      for (int kvf = 0; kvf < 4; ++kvf) {
        f32x4 s = {};
        s = __builtin_amdgcn_mfma_f32_16x16x32_bf16(kf[kvf][0], qf[0], s, 0, 0, 0);
        s = __builtin_amdgcn_mfma_f32_16x16x32_bf16(kf[kvf][1], qf[1], s, 0, 0, 0);
        sc[kvf] = s;
      }
      __builtin_amdgcn_s_setprio(0);

      // bias + mask (all in float; t_off = j - i exactly)
      const float dbase = (float)(kv0 - cbase);
      const bool needMask = (kv0 + 63 > qrb);
      float v[4][4];
#pragma unroll
      for (int kvf = 0; kvf < 4; ++kvf) {
#pragma unroll
        for (int r = 0; r < 4; ++r) {
          const float C = (float)(kvf*16 + (r>>1)*4 + (r&1));
          const float toff = dbase + C;
          float val = fmaf(slope, toff, sc[kvf][r]);
          if (needMask && toff > 0.f) val = -INFINITY;
          v[kvf][r] = val;
        }
      }
      // row max: in-lane tree (compiler fuses to v_max3) + 2 cross-lane
      float q0m = fmaxf(fmaxf(v[0][0], v[0][1]), fmaxf(v[0][2], v[0][3]));
      float q1m = fmaxf(fmaxf(v[1][0], v[1][1]), fmaxf(v[1][2], v[1][3]));
      float q2m = fmaxf(fmaxf(v[2][0], v[2][1]), fmaxf(v[2][2], v[2][3]));
      float q3m = fmaxf(fmaxf(v[3][0], v[3][1]), fmaxf(v[3][2], v[3][3]));
      float mt = fmaxf(fmaxf(q0m, q1m), fmaxf(q2m, q3m));
      mt = fmaxf(mt, __shfl_xor(mt, 16, 64));
      mt = fmaxf(mt, __shfl_xor(mt, 32, 64));

      // defer-max: only rescale when max grew by > 10 (log2 domain => p <= 1024)
      if (__any(mt > m_run + 10.f)) {
        const float mn = fmaxf(m_run, mt);
        const float corr = exp2v(m_run - mn);
        m_run = mn;
        l_run *= corr;
        float co[4];
#pragma unroll
        for (int r = 0; r < 4; ++r) co[r] = __shfl(corr, lg*4 + r, 64);
#pragma unroll
        for (int dt = 0; dt < 4; ++dt)
#pragma unroll
          for (int r = 0; r < 4; ++r) o[dt][r] *= co[r];
      }
      // p = 2^(v - m)
#pragma unroll
      for (int kvf = 0; kvf < 4; ++kvf)
#pragma unroll
        for (int r = 0; r < 4; ++r)
          v[kvf][r] = exp2v(v[kvf][r] - m_run);
      // row sum: in-lane tree + 2 cross-lane
      float s0 = (v[0][0]+v[0][1]) + (v[0][2]+v[0][3]);
      float s1 = (v[1][0]+v[1][1]) + (v[1][2]+v[1][3]);
      float s2 = (v[2][0]+v[2][1]) + (v[2][2]+v[2][3]);
      float s3 = (v[3][0]+v[3][1]) + (v[3][2]+v[3][3]);
      float lt = (s0+s1) + (s2+s3);
      lt += __shfl_xor(lt, 16, 64);
      lt += __shfl_xor(lt, 32, 64);
      l_run += lt;

      // pack P -> bf16 pairs; redistribute via permlane32_swap into PV A-frags
      unsigned pk[4][2];
#pragma unroll
      for (int kvf = 0; kvf < 4; ++kvf) {
        pk[kvf][0] = cvtpk(v[kvf][0], v[kvf][1]);
        pk[kvf][1] = cvtpk(v[kvf][2], v[kvf][3]);
      }
      __builtin_amdgcn_s_setprio(1);
#pragma unroll
      for (int ks = 0; ks < 2; ++ks) {
        unsigned w0 = pk[2*ks][0], w1 = pk[2*ks+1][0];
        pl32swap(w0, w1);
        unsigned w2 = pk[2*ks][1], w3 = pk[2*ks+1][1];
        pl32swap(w2, w3);
        u32x4 wv = {w0, w1, w2, w3};
        const short8 pf = __builtin_bit_cast(short8, wv);
#pragma unroll
        for (int dt = 0; dt < 4; ++dt) {
          const int rv = dt*16 + lr;
          const int cv = (ks*4 + lg) ^ (rv & 7);
          const short8 vf = *(const short8*)(&Vs[cur][rv*64 + cv*8]);
          o[dt] = __builtin_amdgcn_mfma_f32_16x16x32_bf16(pf, vf, o[dt], 0, 0, 0);
        }
      }
      __builtin_amdgcn_s_setprio(0);
    }
    __syncthreads();
    cur ^= 1;
  }

  // epilogue: o[dt][r] holds q = qrb + lg*4 + r, d = dt*16 + lr; l_run lives at q = qrb + lr
  const float inv = 1.f / l_run;
  float li[4];
#pragma unroll
  for (int r = 0; r < 4; ++r) li[r] = __shfl(inv, lg*4 + r, 64);
#pragma unroll
  for (int dt = 0; dt < 4; ++dt)
#pragma unroll
    for (int r = 0; r < 4; ++r) {
      const int iq = qrb + lg*4 + r;
      Ob[(size_t)iq*EMB + dt*16 + lr] = o[dt][r] * li[r];
    }
}

extern "C" void kernel_launch(void* const* d_in, const int* in_sizes, int n_in,
                              void* d_out, int out_size, void* d_ws, size_t ws_size,
                              hipStream_t stream) {
  const float* x = (const float*)d_in[0];
  const float* w = (const float*)d_in[1];
  char* ws = (char*)d_ws;
  if (ws_size < 39845888u) return;
  short* xb = (short*)(ws);
  short* wb = (short*)(ws + 8388608u);
  short* Kb = (short*)(ws + 14680064u);
  short* Qb = (short*)(ws + 23068672u);
  short* Vb = (short*)(ws + 31457280u);
  short* Vt = xb;  // GEMM has consumed xb before vtrans runs
  float* out = (float*)d_out;

  cvt_kernel<<<3584, 256, 0, stream>>>(x, w, xb, wb);
  qkv_gemm<<<dim3(N_GEMM/128, M_GEMM/128), 256, 0, stream>>>(xb, wb, Kb, Qb, Vb);
  vtrans<<<dim3(SEQ/64, TOTAL_B*NH), 256, 0, stream>>>(Vb, Vt);
  attn_kernel<<<dim3(TOTAL_B*NH, 32), 256, 0, stream>>>(Kb, Qb, Vt, out);
}

// Round 4
// 100.388 us; speedup vs baseline: 3.4996x; 1.0705x over previous
//
#include <hip/hip_runtime.h>
#include <hip/hip_bf16.h>
#include <math.h>

#define TOTAL_B 2
#define SEQ 2048
#define EMB 1024
#define NH 16
#define HD 64
#define M_GEMM (TOTAL_B*SEQ)   // 4096
#define N_GEMM (3*EMB)         // 3072
#define K_GEMM EMB             // 1024

typedef __attribute__((ext_vector_type(8))) short short8;
typedef __attribute__((ext_vector_type(4))) float f32x4;
typedef __attribute__((ext_vector_type(4))) unsigned u32x4;

static __device__ __forceinline__ short f2bf(float f) {
  union { float f; unsigned u; } v; v.f = f;
  unsigned r = v.u + 0x7fff + ((v.u >> 16) & 1u);
  return (short)(r >> 16);
}

static __device__ __forceinline__ void gload_lds16(const void* g, void* l) {
  __builtin_amdgcn_global_load_lds(
      (const __attribute__((address_space(1))) void*)(uintptr_t)g,
      (__attribute__((address_space(3))) void*)(uintptr_t)l, 16, 0, 0);
}

static __device__ __forceinline__ float exp2v(float x) {
  float r; asm("v_exp_f32 %0, %1" : "=v"(r) : "v"(x)); return r;
}
static __device__ __forceinline__ unsigned cvtpk(float lo, float hi) {
  unsigned r; asm("v_cvt_pk_bf16_f32 %0, %1, %2" : "=v"(r) : "v"(lo), "v"(hi)); return r;
}
static __device__ __forceinline__ void pl32swap(unsigned &a, unsigned &b) {
  asm("v_permlane32_swap_b32 %0, %1" : "+v"(a), "+v"(b));
}

// ---------------- fp32 -> bf16 convert ----------------
__global__ void cvt_kernel(const float* __restrict__ x, const float* __restrict__ w,
                           short* __restrict__ xb, short* __restrict__ wb) {
  const long nx = (long)M_GEMM * K_GEMM;
  const long nw = (long)N_GEMM * K_GEMM;
  long i = (long)blockIdx.x * blockDim.x + threadIdx.x;
  const long tot = (nx + nw) / 8;
  if (i >= tot) return;
  long e = i * 8;
  const float* s; short* d;
  if (e < nx) { s = x + e; d = xb + e; }
  else        { s = w + (e - nx); d = wb + (e - nx); }
  float4 a = ((const float4*)s)[0];
  float4 b = ((const float4*)s)[1];
  short8 o;
  o[0]=f2bf(a.x); o[1]=f2bf(a.y); o[2]=f2bf(a.z); o[3]=f2bf(a.w);
  o[4]=f2bf(b.x); o[5]=f2bf(b.y); o[6]=f2bf(b.z); o[7]=f2bf(b.w);
  *(short8*)d = o;
}

// ---------------- QKV GEMM ----------------
__global__ __launch_bounds__(256) void qkv_gemm(const short* __restrict__ A, const short* __restrict__ Bm,
                                                short* __restrict__ Kb, short* __restrict__ Qb,
                                                short* __restrict__ Vb) {
  __shared__ __align__(16) short As[128*64];
  __shared__ __align__(16) short Bs[128*64];
  const int tid = threadIdx.x;
  const int lane = tid & 63, wid = tid >> 6;
  const int lr = lane & 15, lg = lane >> 4;
  const int m0 = blockIdx.y * 128, n0 = blockIdx.x * 128;
  const int wm = (wid >> 1) * 64, wn = (wid & 1) * 64;

  f32x4 acc[4][4] = {};

  for (int kt = 0; kt < K_GEMM/64; ++kt) {
#pragma unroll
    for (int i = 0; i < 4; ++i) {
      const int e16 = i*256 + tid;
      const int row = e16 >> 3;
      const int ch  = e16 & 7;
      const int sch = ch ^ (row & 7);
      const short* ga = A  + (size_t)(m0 + row)*K_GEMM + kt*64 + sch*8;
      gload_lds16(ga, As + i*2048 + wid*512);
      const short* gb = Bm + (size_t)(n0 + row)*K_GEMM + kt*64 + sch*8;
      gload_lds16(gb, Bs + i*2048 + wid*512);
    }
    __syncthreads();
#pragma unroll
    for (int kk = 0; kk < 2; ++kk) {
      short8 af[4], bfr[4];
#pragma unroll
      for (int mi = 0; mi < 4; ++mi) {
        const int r = wm + mi*16 + lr;
        const int c = (kk*4 + lg) ^ (r & 7);
        af[mi] = *(const short8*)(As + r*64 + c*8);
      }
#pragma unroll
      for (int ni = 0; ni < 4; ++ni) {
        const int r = wn + ni*16 + lr;
        const int c = (kk*4 + lg) ^ (r & 7);
        bfr[ni] = *(const short8*)(Bs + r*64 + c*8);
      }
#pragma unroll
      for (int mi = 0; mi < 4; ++mi)
#pragma unroll
        for (int ni = 0; ni < 4; ++ni)
          acc[mi][ni] = __builtin_amdgcn_mfma_f32_16x16x32_bf16(af[mi], bfr[ni], acc[mi][ni], 0, 0, 0);
    }
    __syncthreads();
  }

#pragma unroll
  for (int mi = 0; mi < 4; ++mi) {
#pragma unroll
    for (int ni = 0; ni < 4; ++ni) {
#pragma unroll
      for (int r = 0; r < 4; ++r) {
        const int m = m0 + wm + mi*16 + lg*4 + r;
        const int f = n0 + wn + ni*16 + lr;
        const int b = m >> 11, s = m & 2047;
        const int which = f >> 10, fl = f & 1023;
        const int h = fl >> 6, d = fl & 63;
        short* dst = (which == 0) ? Kb : (which == 1) ? Qb : Vb;
        float val = acc[mi][ni][r];
        if (which == 1) val *= 0.04508422f;   // (1/sqrt(E)) * log2(e) folded into Q
        dst[((size_t)((b*NH + h)*SEQ + s))*HD + d] = f2bf(val);
      }
    }
  }
}

// ---------------- V transpose: [bh][s][d] -> [bh][d][s] ----------------
__global__ void vtrans(const short* __restrict__ Vb, short* __restrict__ Vt) {
  __shared__ short t[64][72];
  const int hb = blockIdx.y;
  const int s0 = blockIdx.x * 64;
  const short* src = Vb + ((size_t)hb*SEQ + s0)*HD;
  short* dst = Vt + (size_t)hb*HD*SEQ;
  const int tid = threadIdx.x;
#pragma unroll
  for (int i = 0; i < 2; ++i) {
    const int e = i*2048 + tid*8;
    const int r = e >> 6, c = e & 63;
    short8 v = *(const short8*)(src + (size_t)r*HD + c);
#pragma unroll
    for (int j = 0; j < 8; ++j) t[r][c+j] = v[j];
  }
  __syncthreads();
#pragma unroll
  for (int i = 0; i < 2; ++i) {
    const int e = i*2048 + tid*8;
    const int d = e >> 6, ss = e & 63;
    short8 v;
#pragma unroll
    for (int j = 0; j < 8; ++j) v[j] = t[ss+j][d];
    *(short8*)(dst + (size_t)d*SEQ + s0 + ss) = v;
  }
}

// ---------------- flash attention v4: pipelined QK(t+1) || softmax(t), LPT dispatch ----------------
__global__ __launch_bounds__(256, 4) void attn_kernel(const short* __restrict__ Kb, const short* __restrict__ Qb,
                                                      const short* __restrict__ Vt, float* __restrict__ Out) {
  __shared__ __align__(16) short Ks[3][64*64];   // 3-deep ring: stage t+2 while QK reads t+1
  __shared__ __align__(16) short Vs[2][64*64];   // 2-deep: stage t+1 while PV reads t
  const int tid = threadIdx.x, lane = tid & 63, wid = tid >> 6;
  const int lr = lane & 15, lg = lane >> 4;
  const int bh = blockIdx.x;                  // bh fastest: same bh -> same XCD L2
  const int b = bh >> 4, h = bh & 15;
  const int qt = 31 - blockIdx.y;             // LPT: heaviest blocks dispatch first
  const float slope = exp2f(-0.5f * (float)(h + 1)) * 1.44269504f;  // log2-domain
  const short* Kp = Kb + (size_t)bh * SEQ * HD;
  const short* Qp = Qb + (size_t)bh * SEQ * HD;
  const short* Vp = Vt + (size_t)bh * HD * SEQ;
  float* Ob = Out + (size_t)b * SEQ * EMB + (size_t)h * HD;

  const int q0 = qt * 64, qrb = q0 + wid * 16;
  const int nt = qt + 1;

  short8 qf[2];
#pragma unroll
  for (int kk = 0; kk < 2; ++kk)
    qf[kk] = *(const short8*)(Qp + (size_t)(qrb + lr)*HD + kk*32 + lg*8);

  // A-frag K-row bit-permutation: b3<-i2 b2<-i1 b1<-i3 b0<-i0
  const int bp = ((lr & 4) << 1) | ((lr & 2) << 1) | ((lr & 8) >> 2) | (lr & 1);
  const int cbase = qrb + lr - ((lg & 1) * 8 + (lg >> 1) * 2);

  float m_run = -INFINITY, l_run = 0.f;
  f32x4 o[4] = {};

  auto stageK = [&](int buf, int t) {
    const int kv0 = t * 64;
#pragma unroll
    for (int i = 0; i < 2; ++i) {
      const int e16 = i*256 + tid;
      const int row = e16 >> 3, ch = e16 & 7;
      const int sch = ch ^ (row & 7);
      gload_lds16(Kp + (size_t)(kv0 + row)*HD + sch*8, &Ks[buf][i*2048 + wid*512]);
    }
  };
  auto stageV = [&](int buf, int t) {
    const int kv0 = t * 64;
#pragma unroll
    for (int i = 0; i < 2; ++i) {
      const int e16 = i*256 + tid;
      const int row = e16 >> 3, ch = e16 & 7;
      const int sch = ch ^ (row & 7);
      gload_lds16(Vp + (size_t)row*SEQ + kv0 + sch*8, &Vs[buf][i*2048 + wid*512]);
    }
  };
  auto qkt = [&](int buf, f32x4* sc) {
    short8 kf[4][2];
#pragma unroll
    for (int kvf = 0; kvf < 4; ++kvf) {
      const int row = kvf*16 + bp;
#pragma unroll
      for (int kk = 0; kk < 2; ++kk) {
        const int c = (kk*4 + lg) ^ (row & 7);
        kf[kvf][kk] = *(const short8*)(&Ks[buf][row*64 + c*8]);
      }
    }
    __builtin_amdgcn_s_setprio(1);
#pragma unroll
    for (int kvf = 0; kvf < 4; ++kvf) {
      f32x4 s = {};
      s = __builtin_amdgcn_mfma_f32_16x16x32_bf16(kf[kvf][0], qf[0], s, 0, 0, 0);
      s = __builtin_amdgcn_mfma_f32_16x16x32_bf16(kf[kvf][1], qf[1], s, 0, 0, 0);
      sc[kvf] = s;
    }
    __builtin_amdgcn_s_setprio(0);
  };

  // prologue: stage K0, K1, V0; QK(0)
  stageK(0, 0);
  if (nt > 1) stageK(1, 1);
  stageV(0, 0);
  __syncthreads();
  f32x4 sc_cur[4], sc_next[4];
  qkt(0, sc_cur);

  int k1 = 1, k2 = 2;   // bufK idx of tile t+1, t+2
#pragma unroll 1
  for (int t = 0; t < nt; ++t) {
    const int kv0 = t * 64;
    if (t + 2 < nt) stageK(k2, t + 2);
    if (t + 1 < nt) stageV((t + 1) & 1, t + 1);
    // QK for NEXT tile: overlaps with this tile's softmax (independent)
    if (t + 1 < nt) qkt(k1, sc_next);

    // ---- softmax on sc_cur (tile t) ----
    const float dbase = (float)(kv0 - cbase);
    float v[4][4];
    if (t == nt - 1) {   // only diagonal tile needs the causal mask
#pragma unroll
      for (int kvf = 0; kvf < 4; ++kvf)
#pragma unroll
        for (int r = 0; r < 4; ++r) {
          const float C = (float)(kvf*16 + (r>>1)*4 + (r&1));
          const float toff = dbase + C;
          float val = fmaf(slope, toff, sc_cur[kvf][r]);
          if (toff > 0.f) val = -INFINITY;
          v[kvf][r] = val;
        }
    } else {
#pragma unroll
      for (int kvf = 0; kvf < 4; ++kvf)
#pragma unroll
        for (int r = 0; r < 4; ++r) {
          const float C = (float)(kvf*16 + (r>>1)*4 + (r&1));
          v[kvf][r] = fmaf(slope, dbase + C, sc_cur[kvf][r]);
        }
    }
    float q0m = fmaxf(fmaxf(v[0][0], v[0][1]), fmaxf(v[0][2], v[0][3]));
    float q1m = fmaxf(fmaxf(v[1][0], v[1][1]), fmaxf(v[1][2], v[1][3]));
    float q2m = fmaxf(fmaxf(v[2][0], v[2][1]), fmaxf(v[2][2], v[2][3]));
    float q3m = fmaxf(fmaxf(v[3][0], v[3][1]), fmaxf(v[3][2], v[3][3]));
    float mt = fmaxf(fmaxf(q0m, q1m), fmaxf(q2m, q3m));
    mt = fmaxf(mt, __shfl_xor(mt, 16, 64));
    mt = fmaxf(mt, __shfl_xor(mt, 32, 64));

    if (__any(mt > m_run + 10.f)) {   // defer-max (log2 domain, p <= 2^10)
      const float mn = fmaxf(m_run, mt);
      const float corr = exp2v(m_run - mn);
      m_run = mn;
      l_run *= corr;
      float co[4];
#pragma unroll
      for (int r = 0; r < 4; ++r) co[r] = __shfl(corr, lg*4 + r, 64);
#pragma unroll
      for (int dt = 0; dt < 4; ++dt)
#pragma unroll
        for (int r = 0; r < 4; ++r) o[dt][r] *= co[r];
    }
#pragma unroll
    for (int kvf = 0; kvf < 4; ++kvf)
#pragma unroll
      for (int r = 0; r < 4; ++r)
        v[kvf][r] = exp2v(v[kvf][r] - m_run);
    float s0 = (v[0][0]+v[0][1]) + (v[0][2]+v[0][3]);
    float s1 = (v[1][0]+v[1][1]) + (v[1][2]+v[1][3]);
    float s2 = (v[2][0]+v[2][1]) + (v[2][2]+v[2][3]);
    float s3 = (v[3][0]+v[3][1]) + (v[3][2]+v[3][3]);
    float lt = (s0+s1) + (s2+s3);
    lt += __shfl_xor(lt, 16, 64);
    lt += __shfl_xor(lt, 32, 64);
    l_run += lt;

    // pack P -> bf16; redistribute via permlane32_swap into PV A-frags
    unsigned pk[4][2];
#pragma unroll
    for (int kvf = 0; kvf < 4; ++kvf) {
      pk[kvf][0] = cvtpk(v[kvf][0], v[kvf][1]);
      pk[kvf][1] = cvtpk(v[kvf][2], v[kvf][3]);
    }
    __builtin_amdgcn_s_setprio(1);
#pragma unroll
    for (int ks = 0; ks < 2; ++ks) {
      unsigned w0 = pk[2*ks][0], w1 = pk[2*ks+1][0];
      pl32swap(w0, w1);
      unsigned w2 = pk[2*ks][1], w3 = pk[2*ks+1][1];
      pl32swap(w2, w3);
      u32x4 wv = {w0, w1, w2, w3};
      const short8 pf = __builtin_bit_cast(short8, wv);
#pragma unroll
      for (int dt = 0; dt < 4; ++dt) {
        const int rv = dt*16 + lr;
        const int cv = (ks*4 + lg) ^ (rv & 7);
        const short8 vf = *(const short8*)(&Vs[t & 1][rv*64 + cv*8]);
        o[dt] = __builtin_amdgcn_mfma_f32_16x16x32_bf16(pf, vf, o[dt], 0, 0, 0);
      }
    }
    __builtin_amdgcn_s_setprio(0);

    __syncthreads();
#pragma unroll
    for (int kvf = 0; kvf < 4; ++kvf) sc_cur[kvf] = sc_next[kvf];
    k1 = k2; k2 = (k2 == 2) ? 0 : k2 + 1;
  }

  // epilogue: o[dt][r] holds q = qrb + lg*4 + r, d = dt*16 + lr; l_run at q = qrb + lr
  const float inv = 1.f / l_run;
  float li[4];
#pragma unroll
  for (int r = 0; r < 4; ++r) li[r] = __shfl(inv, lg*4 + r, 64);
#pragma unroll
  for (int dt = 0; dt < 4; ++dt)
#pragma unroll
    for (int r = 0; r < 4; ++r) {
      const int iq = qrb + lg*4 + r;
      Ob[(size_t)iq*EMB + dt*16 + lr] = o[dt][r] * li[r];
    }
}

extern "C" void kernel_launch(void* const* d_in, const int* in_sizes, int n_in,
                              void* d_out, int out_size, void* d_ws, size_t ws_size,
                              hipStream_t stream) {
  const float* x = (const float*)d_in[0];
  const float* w = (const float*)d_in[1];
  char* ws = (char*)d_ws;
  if (ws_size < 39845888u) return;
  short* xb = (short*)(ws);
  short* wb = (short*)(ws + 8388608u);
  short* Kb = (short*)(ws + 14680064u);
  short* Qb = (short*)(ws + 23068672u);
  short* Vb = (short*)(ws + 31457280u);
  short* Vt = xb;  // GEMM has consumed xb before vtrans runs
  float* out = (float*)d_out;

  cvt_kernel<<<3584, 256, 0, stream>>>(x, w, xb, wb);
  qkv_gemm<<<dim3(N_GEMM/128, M_GEMM/128), 256, 0, stream>>>(xb, wb, Kb, Qb, Vb);
  vtrans<<<dim3(SEQ/64, TOTAL_B*NH), 256, 0, stream>>>(Vb, Vt);
  attn_kernel<<<dim3(TOTAL_B*NH, 32), 256, 0, stream>>>(Kb, Qb, Vt, out);
}

// Round 5
// 92.756 us; speedup vs baseline: 3.7876x; 1.0823x over previous
//
#include <hip/hip_runtime.h>
#include <hip/hip_bf16.h>
#include <math.h>

#define TOTAL_B 2
#define SEQ 2048
#define EMB 1024
#define NH 16
#define HD 64
#define M_GEMM (TOTAL_B*SEQ)   // 4096
#define N_GEMM (3*EMB)         // 3072
#define K_GEMM EMB             // 1024

typedef __attribute__((ext_vector_type(8))) short short8;
typedef __attribute__((ext_vector_type(4))) float f32x4;
typedef __attribute__((ext_vector_type(4))) unsigned u32x4;

static __device__ __forceinline__ short f2bf(float f) {
  union { float f; unsigned u; } v; v.f = f;
  unsigned r = v.u + 0x7fff + ((v.u >> 16) & 1u);
  return (short)(r >> 16);
}

static __device__ __forceinline__ void gload_lds16(const void* g, void* l) {
  __builtin_amdgcn_global_load_lds(
      (const __attribute__((address_space(1))) void*)(uintptr_t)g,
      (__attribute__((address_space(3))) void*)(uintptr_t)l, 16, 0, 0);
}

static __device__ __forceinline__ float exp2v(float x) {
  float r; asm("v_exp_f32 %0, %1" : "=v"(r) : "v"(x)); return r;
}
static __device__ __forceinline__ unsigned cvtpk(float lo, float hi) {
  unsigned r; asm("v_cvt_pk_bf16_f32 %0, %1, %2" : "=v"(r) : "v"(lo), "v"(hi)); return r;
}
static __device__ __forceinline__ void pl32swap(unsigned &a, unsigned &b) {
  asm("v_permlane32_swap_b32 %0, %1" : "+v"(a), "+v"(b));
}

// ---------------- fp32 -> bf16 convert ----------------
__global__ void cvt_kernel(const float* __restrict__ x, const float* __restrict__ w,
                           short* __restrict__ xb, short* __restrict__ wb) {
  const long nx = (long)M_GEMM * K_GEMM;
  const long nw = (long)N_GEMM * K_GEMM;
  long i = (long)blockIdx.x * blockDim.x + threadIdx.x;
  const long tot = (nx + nw) / 8;
  if (i >= tot) return;
  long e = i * 8;
  const float* s; short* d;
  if (e < nx) { s = x + e; d = xb + e; }
  else        { s = w + (e - nx); d = wb + (e - nx); }
  float4 a = ((const float4*)s)[0];
  float4 b = ((const float4*)s)[1];
  short8 o;
  o[0]=f2bf(a.x); o[1]=f2bf(a.y); o[2]=f2bf(a.z); o[3]=f2bf(a.w);
  o[4]=f2bf(b.x); o[5]=f2bf(b.y); o[6]=f2bf(b.z); o[7]=f2bf(b.w);
  *(short8*)d = o;
}

// ---------------- QKV GEMM v2: 256x192 tile, BK=64, 8 waves, dbuf LDS, 4-phase interleave ----------------
// grid (16,16) = 256 blocks = 1/CU. LDS 112KB: A[2][256][64], B[2][192][64] bf16, chunk^(row&7) swizzle.
__global__ __launch_bounds__(512, 2) void qkv_gemm(const short* __restrict__ A, const short* __restrict__ Bm,
                                                   short* __restrict__ Kb, short* __restrict__ Qb,
                                                   short* __restrict__ Vb) {
  __shared__ __align__(16) short lds[57344];   // shorts: A bufs [0,32768), B bufs [32768,57344)
  const int tid = threadIdx.x;
  const int lane = tid & 63;
  const int wid = tid >> 6;
  const int lr = lane & 15, lg = lane >> 4;
  const int m0 = blockIdx.y * 256, n0 = blockIdx.x * 192;
  const int wr = wid >> 1;        // 0..3 -> 64 m-rows each
  const int wc = wid & 1;         // 0..1 -> 96 n-cols each
  const int srcRow = tid >> 3;                     // 0..63
  const int srcCh  = (tid & 7) ^ (srcRow & 7);     // pre-swizzled global source chunk

  f32x4 acc[4][6] = {};

  auto stageA = [&](int buf, int kt, int u) {
    const int row = u*64 + srcRow;                 // 0..255
    gload_lds16(A + (size_t)(m0 + row)*K_GEMM + kt*64 + srcCh*8,
                &lds[buf*16384 + u*4096 + tid*8]);
  };
  auto stageB = [&](int buf, int kt, int u) {
    const int row = u*64 + srcRow;                 // 0..191
    gload_lds16(Bm + (size_t)(n0 + row)*K_GEMM + kt*64 + srcCh*8,
                &lds[32768 + buf*12288 + u*4096 + tid*8]);
  };
  auto readA = [&](int buf, int mi, int kk) -> short8 {
    const int r = wr*64 + mi*16 + lr;
    const int c = (kk*4 + lg) ^ (r & 7);
    return *(const short8*)(&lds[buf*16384 + r*64 + c*8]);
  };
  auto readB = [&](int buf, int nj, int kk) -> short8 {
    const int r = wc*96 + nj*16 + lr;
    const int c = (kk*4 + lg) ^ (r & 7);
    return *(const short8*)(&lds[32768 + buf*12288 + r*64 + c*8]);
  };

  // prologue: stage tile 0 fully, drain, barrier
#pragma unroll
  for (int u = 0; u < 4; ++u) stageA(0, 0, u);
#pragma unroll
  for (int u = 0; u < 3; ++u) stageB(0, 0, u);
  asm volatile("s_waitcnt vmcnt(0)" ::: "memory");
  __builtin_amdgcn_s_barrier();

  short8 aq[2][2], bq[6][2];
  const int NT = K_GEMM / 64;    // 16
#pragma unroll 1
  for (int kt = 0; kt < NT; ++kt) {
    const int buf = kt & 1, nb = buf ^ 1;
    const bool more = (kt + 1 < NT);

    // ---- phase 0: read A(mi0,1) + B(nj0..2); stage A units 0,1 of next tile
#pragma unroll
    for (int kk = 0; kk < 2; ++kk) {
      aq[0][kk] = readA(buf, 0, kk); aq[1][kk] = readA(buf, 1, kk);
      bq[0][kk] = readB(buf, 0, kk); bq[1][kk] = readB(buf, 1, kk); bq[2][kk] = readB(buf, 2, kk);
    }
    if (more) { stageA(nb, kt+1, 0); stageA(nb, kt+1, 1); }
    __builtin_amdgcn_s_barrier();
    asm volatile("s_waitcnt lgkmcnt(0)" ::: "memory");
    __builtin_amdgcn_sched_barrier(0);
    __builtin_amdgcn_s_setprio(1);
#pragma unroll
    for (int mi = 0; mi < 2; ++mi)
#pragma unroll
      for (int nj = 0; nj < 3; ++nj)
#pragma unroll
        for (int kk = 0; kk < 2; ++kk)
          acc[mi][nj] = __builtin_amdgcn_mfma_f32_16x16x32_bf16(aq[mi][kk], bq[nj][kk], acc[mi][nj], 0, 0, 0);
    __builtin_amdgcn_s_setprio(0);
    __builtin_amdgcn_sched_barrier(0);
    __builtin_amdgcn_s_barrier();

    // ---- phase 1: read B(nj3..5); stage A units 2,3
#pragma unroll
    for (int kk = 0; kk < 2; ++kk) {
      bq[3][kk] = readB(buf, 3, kk); bq[4][kk] = readB(buf, 4, kk); bq[5][kk] = readB(buf, 5, kk);
    }
    if (more) { stageA(nb, kt+1, 2); stageA(nb, kt+1, 3); }
    __builtin_amdgcn_s_barrier();
    asm volatile("s_waitcnt lgkmcnt(0)" ::: "memory");
    __builtin_amdgcn_sched_barrier(0);
    __builtin_amdgcn_s_setprio(1);
#pragma unroll
    for (int mi = 0; mi < 2; ++mi)
#pragma unroll
      for (int nj = 3; nj < 6; ++nj)
#pragma unroll
        for (int kk = 0; kk < 2; ++kk)
          acc[mi][nj] = __builtin_amdgcn_mfma_f32_16x16x32_bf16(aq[mi][kk], bq[nj][kk], acc[mi][nj], 0, 0, 0);
    __builtin_amdgcn_s_setprio(0);
    __builtin_amdgcn_sched_barrier(0);
    __builtin_amdgcn_s_barrier();

    // ---- phase 2: read A(mi2,3) (overwrite aq); stage B units 0,1
#pragma unroll
    for (int kk = 0; kk < 2; ++kk) {
      aq[0][kk] = readA(buf, 2, kk); aq[1][kk] = readA(buf, 3, kk);
    }
    if (more) { stageB(nb, kt+1, 0); stageB(nb, kt+1, 1); }
    __builtin_amdgcn_s_barrier();
    asm volatile("s_waitcnt lgkmcnt(0)" ::: "memory");
    __builtin_amdgcn_sched_barrier(0);
    __builtin_amdgcn_s_setprio(1);
#pragma unroll
    for (int mi = 0; mi < 2; ++mi)
#pragma unroll
      for (int nj = 3; nj < 6; ++nj)
#pragma unroll
        for (int kk = 0; kk < 2; ++kk)
          acc[mi+2][nj] = __builtin_amdgcn_mfma_f32_16x16x32_bf16(aq[mi][kk], bq[nj][kk], acc[mi+2][nj], 0, 0, 0);
    __builtin_amdgcn_s_setprio(0);
    __builtin_amdgcn_sched_barrier(0);
    __builtin_amdgcn_s_barrier();

    // ---- phase 3: read B(nj0..2) again; stage B unit 2
#pragma unroll
    for (int kk = 0; kk < 2; ++kk) {
      bq[0][kk] = readB(buf, 0, kk); bq[1][kk] = readB(buf, 1, kk); bq[2][kk] = readB(buf, 2, kk);
    }
    if (more) { stageB(nb, kt+1, 2); }
    __builtin_amdgcn_s_barrier();
    asm volatile("s_waitcnt lgkmcnt(0)" ::: "memory");
    __builtin_amdgcn_sched_barrier(0);
    __builtin_amdgcn_s_setprio(1);
#pragma unroll
    for (int mi = 0; mi < 2; ++mi)
#pragma unroll
      for (int nj = 0; nj < 3; ++nj)
#pragma unroll
        for (int kk = 0; kk < 2; ++kk)
          acc[mi+2][nj] = __builtin_amdgcn_mfma_f32_16x16x32_bf16(aq[mi][kk], bq[nj][kk], acc[mi+2][nj], 0, 0, 0);
    __builtin_amdgcn_s_setprio(0);
    __builtin_amdgcn_sched_barrier(0);

    // ---- tile boundary: all of tile t consumed; wait next tile's staging
    asm volatile("s_waitcnt vmcnt(0)" ::: "memory");
    __builtin_amdgcn_s_barrier();
  }

  // epilogue: C row m = wr*64+mi*16+lg*4+r, col f = wc*96+nj*16+lr
#pragma unroll
  for (int nj = 0; nj < 6; ++nj) {
    const int f = n0 + wc*96 + nj*16 + lr;
    const int which = f >> 10, fl = f & 1023;
    const int h = fl >> 6, d = fl & 63;
    short* dst = (which == 0) ? Kb : (which == 1) ? Qb : Vb;
    const float scale = (which == 1) ? 0.04508422f : 1.0f;  // (1/sqrt(E))*log2(e) folded into Q
    short* base = dst + (size_t)h*SEQ*HD + d;
#pragma unroll
    for (int mi = 0; mi < 4; ++mi)
#pragma unroll
      for (int r = 0; r < 4; ++r) {
        const int m = m0 + wr*64 + mi*16 + lg*4 + r;
        const int b = m >> 11, s = m & 2047;
        base[((size_t)b*NH*SEQ + s)*HD] = f2bf(acc[mi][nj][r] * scale);
      }
  }
}

// ---------------- V transpose: [bh][s][d] -> [bh][d][s] ----------------
__global__ void vtrans(const short* __restrict__ Vb, short* __restrict__ Vt) {
  __shared__ short t[64][72];
  const int hb = blockIdx.y;
  const int s0 = blockIdx.x * 64;
  const short* src = Vb + ((size_t)hb*SEQ + s0)*HD;
  short* dst = Vt + (size_t)hb*HD*SEQ;
  const int tid = threadIdx.x;
#pragma unroll
  for (int i = 0; i < 2; ++i) {
    const int e = i*2048 + tid*8;
    const int r = e >> 6, c = e & 63;
    short8 v = *(const short8*)(src + (size_t)r*HD + c);
#pragma unroll
    for (int j = 0; j < 8; ++j) t[r][c+j] = v[j];
  }
  __syncthreads();
#pragma unroll
  for (int i = 0; i < 2; ++i) {
    const int e = i*2048 + tid*8;
    const int d = e >> 6, ss = e & 63;
    short8 v;
#pragma unroll
    for (int j = 0; j < 8; ++j) v[j] = t[ss+j][d];
    *(short8*)(dst + (size_t)d*SEQ + s0 + ss) = v;
  }
}

// ---------------- flash attention v4: pipelined QK(t+1) || softmax(t), LPT dispatch ----------------
__global__ __launch_bounds__(256, 4) void attn_kernel(const short* __restrict__ Kb, const short* __restrict__ Qb,
                                                      const short* __restrict__ Vt, float* __restrict__ Out) {
  __shared__ __align__(16) short Ks[3][64*64];   // 3-deep ring: stage t+2 while QK reads t+1
  __shared__ __align__(16) short Vs[2][64*64];   // 2-deep: stage t+1 while PV reads t
  const int tid = threadIdx.x, lane = tid & 63, wid = tid >> 6;
  const int lr = lane & 15, lg = lane >> 4;
  const int bh = blockIdx.x;                  // bh fastest: same bh -> same XCD L2
  const int b = bh >> 4, h = bh & 15;
  const int qt = 31 - blockIdx.y;             // LPT: heaviest blocks dispatch first
  const float slope = exp2f(-0.5f * (float)(h + 1)) * 1.44269504f;  // log2-domain
  const short* Kp = Kb + (size_t)bh * SEQ * HD;
  const short* Qp = Qb + (size_t)bh * SEQ * HD;
  const short* Vp = Vt + (size_t)bh * HD * SEQ;
  float* Ob = Out + (size_t)b * SEQ * EMB + (size_t)h * HD;

  const int q0 = qt * 64, qrb = q0 + wid * 16;
  const int nt = qt + 1;

  short8 qf[2];
#pragma unroll
  for (int kk = 0; kk < 2; ++kk)
    qf[kk] = *(const short8*)(Qp + (size_t)(qrb + lr)*HD + kk*32 + lg*8);

  // A-frag K-row bit-permutation: b3<-i2 b2<-i1 b1<-i3 b0<-i0
  const int bp = ((lr & 4) << 1) | ((lr & 2) << 1) | ((lr & 8) >> 2) | (lr & 1);
  const int cbase = qrb + lr - ((lg & 1) * 8 + (lg >> 1) * 2);

  float m_run = -INFINITY, l_run = 0.f;
  f32x4 o[4] = {};

  auto stageK = [&](int buf, int t) {
    const int kv0 = t * 64;
#pragma unroll
    for (int i = 0; i < 2; ++i) {
      const int e16 = i*256 + tid;
      const int row = e16 >> 3, ch = e16 & 7;
      const int sch = ch ^ (row & 7);
      gload_lds16(Kp + (size_t)(kv0 + row)*HD + sch*8, &Ks[buf][i*2048 + wid*512]);
    }
  };
  auto stageV = [&](int buf, int t) {
    const int kv0 = t * 64;
#pragma unroll
    for (int i = 0; i < 2; ++i) {
      const int e16 = i*256 + tid;
      const int row = e16 >> 3, ch = e16 & 7;
      const int sch = ch ^ (row & 7);
      gload_lds16(Vp + (size_t)row*SEQ + kv0 + sch*8, &Vs[buf][i*2048 + wid*512]);
    }
  };
  auto qkt = [&](int buf, f32x4* sc) {
    short8 kf[4][2];
#pragma unroll
    for (int kvf = 0; kvf < 4; ++kvf) {
      const int row = kvf*16 + bp;
#pragma unroll
      for (int kk = 0; kk < 2; ++kk) {
        const int c = (kk*4 + lg) ^ (row & 7);
        kf[kvf][kk] = *(const short8*)(&Ks[buf][row*64 + c*8]);
      }
    }
    __builtin_amdgcn_s_setprio(1);
#pragma unroll
    for (int kvf = 0; kvf < 4; ++kvf) {
      f32x4 s = {};
      s = __builtin_amdgcn_mfma_f32_16x16x32_bf16(kf[kvf][0], qf[0], s, 0, 0, 0);
      s = __builtin_amdgcn_mfma_f32_16x16x32_bf16(kf[kvf][1], qf[1], s, 0, 0, 0);
      sc[kvf] = s;
    }
    __builtin_amdgcn_s_setprio(0);
  };

  // prologue: stage K0, K1, V0; QK(0)
  stageK(0, 0);
  if (nt > 1) stageK(1, 1);
  stageV(0, 0);
  __syncthreads();
  f32x4 sc_cur[4], sc_next[4];
  qkt(0, sc_cur);

  int k1 = 1, k2 = 2;   // bufK idx of tile t+1, t+2
#pragma unroll 1
  for (int t = 0; t < nt; ++t) {
    const int kv0 = t * 64;
    if (t + 2 < nt) stageK(k2, t + 2);
    if (t + 1 < nt) stageV((t + 1) & 1, t + 1);
    // QK for NEXT tile: overlaps with this tile's softmax (independent)
    if (t + 1 < nt) qkt(k1, sc_next);

    // ---- softmax on sc_cur (tile t) ----
    const float dbase = (float)(kv0 - cbase);
    float v[4][4];
    if (t == nt - 1) {   // only diagonal tile needs the causal mask
#pragma unroll
      for (int kvf = 0; kvf < 4; ++kvf)
#pragma unroll
        for (int r = 0; r < 4; ++r) {
          const float C = (float)(kvf*16 + (r>>1)*4 + (r&1));
          const float toff = dbase + C;
          float val = fmaf(slope, toff, sc_cur[kvf][r]);
          if (toff > 0.f) val = -INFINITY;
          v[kvf][r] = val;
        }
    } else {
#pragma unroll
      for (int kvf = 0; kvf < 4; ++kvf)
#pragma unroll
        for (int r = 0; r < 4; ++r) {
          const float C = (float)(kvf*16 + (r>>1)*4 + (r&1));
          v[kvf][r] = fmaf(slope, dbase + C, sc_cur[kvf][r]);
        }
    }
    float q0m = fmaxf(fmaxf(v[0][0], v[0][1]), fmaxf(v[0][2], v[0][3]));
    float q1m = fmaxf(fmaxf(v[1][0], v[1][1]), fmaxf(v[1][2], v[1][3]));
    float q2m = fmaxf(fmaxf(v[2][0], v[2][1]), fmaxf(v[2][2], v[2][3]));
    float q3m = fmaxf(fmaxf(v[3][0], v[3][1]), fmaxf(v[3][2], v[3][3]));
    float mt = fmaxf(fmaxf(q0m, q1m), fmaxf(q2m, q3m));
    mt = fmaxf(mt, __shfl_xor(mt, 16, 64));
    mt = fmaxf(mt, __shfl_xor(mt, 32, 64));

    if (__any(mt > m_run + 10.f)) {   // defer-max (log2 domain, p <= 2^10)
      const float mn = fmaxf(m_run, mt);
      const float corr = exp2v(m_run - mn);
      m_run = mn;
      l_run *= corr;
      float co[4];
#pragma unroll
      for (int r = 0; r < 4; ++r) co[r] = __shfl(corr, lg*4 + r, 64);
#pragma unroll
      for (int dt = 0; dt < 4; ++dt)
#pragma unroll
        for (int r = 0; r < 4; ++r) o[dt][r] *= co[r];
    }
#pragma unroll
    for (int kvf = 0; kvf < 4; ++kvf)
#pragma unroll
      for (int r = 0; r < 4; ++r)
        v[kvf][r] = exp2v(v[kvf][r] - m_run);
    float s0 = (v[0][0]+v[0][1]) + (v[0][2]+v[0][3]);
    float s1 = (v[1][0]+v[1][1]) + (v[1][2]+v[1][3]);
    float s2 = (v[2][0]+v[2][1]) + (v[2][2]+v[2][3]);
    float s3 = (v[3][0]+v[3][1]) + (v[3][2]+v[3][3]);
    float lt = (s0+s1) + (s2+s3);
    lt += __shfl_xor(lt, 16, 64);
    lt += __shfl_xor(lt, 32, 64);
    l_run += lt;

    // pack P -> bf16; redistribute via permlane32_swap into PV A-frags
    unsigned pk[4][2];
#pragma unroll
    for (int kvf = 0; kvf < 4; ++kvf) {
      pk[kvf][0] = cvtpk(v[kvf][0], v[kvf][1]);
      pk[kvf][1] = cvtpk(v[kvf][2], v[kvf][3]);
    }
    __builtin_amdgcn_s_setprio(1);
#pragma unroll
    for (int ks = 0; ks < 2; ++ks) {
      unsigned w0 = pk[2*ks][0], w1 = pk[2*ks+1][0];
      pl32swap(w0, w1);
      unsigned w2 = pk[2*ks][1], w3 = pk[2*ks+1][1];
      pl32swap(w2, w3);
      u32x4 wv = {w0, w1, w2, w3};
      const short8 pf = __builtin_bit_cast(short8, wv);
#pragma unroll
      for (int dt = 0; dt < 4; ++dt) {
        const int rv = dt*16 + lr;
        const int cv = (ks*4 + lg) ^ (rv & 7);
        const short8 vf = *(const short8*)(&Vs[t & 1][rv*64 + cv*8]);
        o[dt] = __builtin_amdgcn_mfma_f32_16x16x32_bf16(pf, vf, o[dt], 0, 0, 0);
      }
    }
    __builtin_amdgcn_s_setprio(0);

    __syncthreads();
#pragma unroll
    for (int kvf = 0; kvf < 4; ++kvf) sc_cur[kvf] = sc_next[kvf];
    k1 = k2; k2 = (k2 == 2) ? 0 : k2 + 1;
  }

  // epilogue: o[dt][r] holds q = qrb + lg*4 + r, d = dt*16 + lr; l_run at q = qrb + lr
  const float inv = 1.f / l_run;
  float li[4];
#pragma unroll
  for (int r = 0; r < 4; ++r) li[r] = __shfl(inv, lg*4 + r, 64);
#pragma unroll
  for (int dt = 0; dt < 4; ++dt)
#pragma unroll
    for (int r = 0; r < 4; ++r) {
      const int iq = qrb + lg*4 + r;
      Ob[(size_t)iq*EMB + dt*16 + lr] = o[dt][r] * li[r];
    }
}

extern "C" void kernel_launch(void* const* d_in, const int* in_sizes, int n_in,
                              void* d_out, int out_size, void* d_ws, size_t ws_size,
                              hipStream_t stream) {
  const float* x = (const float*)d_in[0];
  const float* w = (const float*)d_in[1];
  char* ws = (char*)d_ws;
  if (ws_size < 39845888u) return;
  short* xb = (short*)(ws);
  short* wb = (short*)(ws + 8388608u);
  short* Kb = (short*)(ws + 14680064u);
  short* Qb = (short*)(ws + 23068672u);
  short* Vb = (short*)(ws + 31457280u);
  short* Vt = xb;  // GEMM has consumed xb before vtrans runs
  float* out = (float*)d_out;

  cvt_kernel<<<3584, 256, 0, stream>>>(x, w, xb, wb);
  qkv_gemm<<<dim3(N_GEMM/192, M_GEMM/256), 512, 0, stream>>>(xb, wb, Kb, Qb, Vb);
  vtrans<<<dim3(SEQ/64, TOTAL_B*NH), 256, 0, stream>>>(Vb, Vt);
  attn_kernel<<<dim3(TOTAL_B*NH, 32), 256, 0, stream>>>(Kb, Qb, Vt, out);
}